// Round 8
// baseline (109.728 us; speedup 1.0000x reference)
//
#include <hip/hip_runtime.h>

// ---------- constants (problem is fixed-shape) ----------
#define BB   16
#define PP   256
#define BP   4096        // B*P
#define DMODEL 1024
#define VV   1000
#define DLLM 4096
#define HH   16
#define DK   64
#define HDK  1024        // H*DK

using f32x4 = __attribute__((ext_vector_type(4))) float;
using s16x8 = __attribute__((ext_vector_type(8))) short;
using us8   = __attribute__((ext_vector_type(8))) unsigned short;

__device__ __forceinline__ unsigned short f2bf(float f) {
    unsigned int u = __builtin_bit_cast(unsigned int, f);
    u = (u + 0x7FFFu + ((u >> 16) & 1u)) >> 16;   // RNE
    return (unsigned short)u;
}

__device__ __forceinline__ void gload_lds16(const unsigned short* g, unsigned short* lds) {
    __builtin_amdgcn_global_load_lds(
        (const __attribute__((address_space(1))) void*)g,
        (__attribute__((address_space(3))) void*)lds,
        16, 0, 0);
}

// ---------- MEGA1: colsum_partial ∪ cast_bf16 ∪ transpose(Wq) ∪ transpose(Wo) ----------
// fully vectorized: float4 loads everywhere, ushort4/8 stores.
__device__ __forceinline__ void transpose_body(const float* __restrict__ src,
                                               unsigned short* __restrict__ dst,
                                               int R, int C, int bx, int by, int t,
                                               float (*tile)[33]) {
    int x = t & 7, y = t >> 3;                      // 8 x 32
    int c0 = bx * 32, r0 = by * 32;
    float4 v = *reinterpret_cast<const float4*>(&src[(size_t)(r0 + y) * C + c0 + x * 4]);
    tile[y][x * 4 + 0] = v.x; tile[y][x * 4 + 1] = v.y;
    tile[y][x * 4 + 2] = v.z; tile[y][x * 4 + 3] = v.w;
    __syncthreads();
    ushort4 o = make_ushort4(f2bf(tile[x * 4 + 0][y]), f2bf(tile[x * 4 + 1][y]),
                             f2bf(tile[x * 4 + 2][y]), f2bf(tile[x * 4 + 3][y]));
    *reinterpret_cast<ushort4*>(&dst[(size_t)(c0 + y) * R + r0 + x * 4]) = o;
}

__global__ void mega1(const float* __restrict__ src0, const float* __restrict__ src1,
                      float* __restrict__ part1,
                      const float* __restrict__ target, unsigned short* __restrict__ tgt_bf,
                      const float* __restrict__ Wq, unsigned short* __restrict__ wq_t,
                      const float* __restrict__ Wo, unsigned short* __restrict__ wo_t) {
    __shared__ float tile[32][33];
    int b = blockIdx.x, t = threadIdx.x;
    if (b < 320) {
        // colsum partials: z(2) x chunk(40) x xblk(4); float4 per lane
        int z = b / 160, rem = b % 160, y = rem >> 2, x = rem & 3;
        int col4 = x * 256 + t;                     // 0..1023 (of DLLM/4)
        const float4* src = reinterpret_cast<const float4*>(z ? src1 : src0);
        int r0 = y * 25;
        float4 acc = make_float4(0.f, 0.f, 0.f, 0.f);
        for (int r = 0; r < 25; ++r) {
            float4 v = src[(size_t)(r0 + r) * (DLLM / 4) + col4];
            acc.x += v.x; acc.y += v.y; acc.z += v.z; acc.w += v.w;
        }
        reinterpret_cast<float4*>(part1)[(size_t)(z * 40 + y) * (DLLM / 4) + col4] = acc;
    } else if (b < 320 + 2048) {
        // cast target f32 -> bf16, 8 elems/thread
        int idx = (b - 320) * 256 + t;              // < 524288
        float4 v0 = reinterpret_cast<const float4*>(target)[idx * 2];
        float4 v1 = reinterpret_cast<const float4*>(target)[idx * 2 + 1];
        us8 o = { f2bf(v0.x), f2bf(v0.y), f2bf(v0.z), f2bf(v0.w),
                  f2bf(v1.x), f2bf(v1.y), f2bf(v1.z), f2bf(v1.w) };
        *reinterpret_cast<us8*>(&tgt_bf[(size_t)idx * 8]) = o;
    } else if (b < 320 + 2048 + 1024) {
        int b2 = b - 2368;
        transpose_body(Wq, wq_t, DMODEL, HDK, b2 & 31, b2 >> 5, t, tile);
    } else {
        int b2 = b - 3392;
        transpose_body(Wo, wo_t, HDK, DLLM, b2 & 127, b2 >> 7, t, tile);
    }
}

// ---------- gemv_partial2 (inlines colsum_reduce) ----------
__global__ void gemv_partial2(const float* __restrict__ Wk, const float* __restrict__ Wv,
                              const float* __restrict__ part1, float* __restrict__ part2) {
    __shared__ float vec[64];
    int c     = blockIdx.x * 256 + threadIdx.x;
    int chunk = blockIdx.y;
    int z     = blockIdx.z;
    const float* W = z ? Wv : Wk;
    if (threadIdx.x < 64) {
        int r = chunk * 64 + threadIdx.x;
        float a = 0.f;
        for (int p = 0; p < 40; ++p)
            a += part1[(size_t)(z * 40 + p) * DLLM + r];
        vec[threadIdx.x] = a;
    }
    __syncthreads();
    float acc = 0.f;
    int r0 = chunk * 64;
    for (int r = 0; r < 64; ++r)
        acc += vec[r] * W[(size_t)(r0 + r) * HDK + c];
    part2[((z * 64 + chunk) * HDK) + c] = acc;
}

__global__ void gemv_reduce(const float* __restrict__ part,
                            const float* __restrict__ bk, const float* __restrict__ bv,
                            float* __restrict__ kvsum) {
    int idx = blockIdx.x * 256 + threadIdx.x;
    int z = idx >> 10, c = idx & 1023;
    float acc = 0.f;
    for (int ch = 0; ch < 64; ++ch) acc += part[(size_t)(z * 64 + ch) * HDK + c];
    acc += (float)VV * (z ? bv[c] : bk[c]);
    kvsum[idx] = acc;
}

// ---------- counted-vmcnt GEMM, 3-buffer BK=32, distance-2 prefetch ----------
// NEW this round: (1) rect-per-XCD swizzle — each XCD owns an 8x8 block rect
// so its L2 working set is A-panel + B-panel (<= ~6MB) instead of streaming
// the whole B matrix; (2) nontemporal C stores (EPI=0) keep the 64MB f32
// write burst from evicting A/B panels out of L2.
// Swizzle requires grid == 512 (64 blocks per XCD, rect 8x8).
// LDS swizzle: phys 16B-slot = logical ^ (super-row & 7), both sides (0 confl).
// EPI=0: C(f32)=A*B^T+bias (NT stores). EPI=1: fused per-head softmax -> bf16 R.
template<int EPI, int BMt, int BNt, int WM, int WN>
__global__ __launch_bounds__(WM * WN * 64, 2)
void gemm_ctd3(const unsigned short* __restrict__ A, const unsigned short* __restrict__ Bt,
               float* __restrict__ C, const float* __restrict__ bias,
               const float* __restrict__ kvsum, unsigned short* __restrict__ R,
               int N, int K, int gDivR) {
    constexpr int WAVES = WM * WN;
    constexpr int Mw = BMt / WM;
    constexpr int M_REP = Mw / 16;
    constexpr int NA = BMt * 32 / (WAVES * 512);   // A gloads per thread per stage
    constexpr int NB = BNt * 32 / (WAVES * 512);   // B gloads per thread per stage
    constexpr int NST = NA + NB;
    static_assert(BNt / WN == 64, "wave col span must be 64");
    static_assert(NA >= 1 && NB >= 1, "staging geometry");

    __shared__ __align__(16) unsigned short Asm[3][BMt * 32];
    __shared__ __align__(16) unsigned short Bsm[3][BNt * 32];

    // rect-per-XCD swizzle: xcd = bid&7 owns an 8(bm) x 8(bn) rect of blocks.
    // bm-group = xcd / gDivR, bn-group = xcd % gDivR  (gDivR = gx/8).
    const int xcd = blockIdx.x & 7, l = blockIdx.x >> 3;   // l in [0,64)
    const int bm = ((xcd / gDivR) * 8 + (l & 7)) * BMt;
    const int bn = ((xcd % gDivR) * 8 + (l >> 3)) * BNt;

    const int t = threadIdx.x;
    const int w = t >> 6, lane = t & 63;
    const int wr = w / WN, wc = w % WN;
    const int l15 = lane & 15, kgrp = lane >> 4;

    // staging map: issue covers 8 super-rows (128B each); lane -> sr+=lane>>3,
    // phys slot lane&7; global content for phys slot s at sr = (s ^ (sr&7)).
    size_t goffA[NA], goffB[NB];
    int ldsoA[NA], ldsoB[NB];
    {
        int s8 = lane & 7, jj = lane >> 3;
#pragma unroll
        for (int i = 0; i < NA; ++i) {
            int sr = (i * WAVES + w) * 8 + jj;
            int x = s8 ^ (sr & 7);
            goffA[i] = (size_t)(bm + sr * 2 + (x >> 2)) * K + (x & 3) * 8;
            ldsoA[i] = (i * WAVES + w) * 512;
        }
#pragma unroll
        for (int i = 0; i < NB; ++i) {
            int sr = (i * WAVES + w) * 8 + jj;
            int x = s8 ^ (sr & 7);
            goffB[i] = (size_t)(bn + sr * 2 + (x >> 2)) * K + (x & 3) * 8;
            ldsoB[i] = (i * WAVES + w) * 512;
        }
    }
    // swizzled ds_read offsets (ushort units)
    int ra[M_REP], rb[4];
#pragma unroll
    for (int m = 0; m < M_REP; ++m) {
        int r = wr * Mw + m * 16 + l15;
        int s8 = (kgrp + 4 * (r & 1)) ^ ((r >> 1) & 7);
        ra[m] = (r >> 1) * 64 + s8 * 8;
    }
#pragma unroll
    for (int n = 0; n < 4; ++n) {
        int r = wc * 64 + n * 16 + l15;
        int s8 = (kgrp + 4 * (r & 1)) ^ ((r >> 1) & 7);
        rb[n] = (r >> 1) * 64 + s8 * 8;
    }

    f32x4 acc[M_REP][4] = {};

#define STAGE(t_, b_) do { size_t k0_ = (size_t)(t_) * 32;             \
    _Pragma("unroll")                                                  \
    for (int i_ = 0; i_ < NA; ++i_)                                    \
        gload_lds16(A + goffA[i_] + k0_, &Asm[b_][ldsoA[i_]]);         \
    _Pragma("unroll")                                                  \
    for (int i_ = 0; i_ < NB; ++i_)                                    \
        gload_lds16(Bt + goffB[i_] + k0_, &Bsm[b_][ldsoB[i_]]); } while (0)

#define WAIT_VM(n_) asm volatile("s_waitcnt vmcnt(" #n_ ")" ::: "memory")

    const int nT = K >> 5;
    STAGE(0, 0); STAGE(1, 1);
    if constexpr (NST == 6) WAIT_VM(6); else if constexpr (NST == 4) WAIT_VM(4); else WAIT_VM(3);
    __builtin_amdgcn_s_barrier();

    int cur = 0;
    for (int tk = 0; tk < nT; ++tk) {
        s16x8 af[M_REP], bfr[4];
#pragma unroll
        for (int m = 0; m < M_REP; ++m)
            af[m] = *reinterpret_cast<const s16x8*>(&Asm[cur][ra[m]]);
#pragma unroll
        for (int n = 0; n < 4; ++n)
            bfr[n] = *reinterpret_cast<const s16x8*>(&Bsm[cur][rb[n]]);
        if (tk + 2 < nT) STAGE(tk + 2, cur == 0 ? 2 : cur - 1);   // (cur+2)%3
        __builtin_amdgcn_s_setprio(1);
#pragma unroll
        for (int m = 0; m < M_REP; ++m)
#pragma unroll
            for (int n = 0; n < 4; ++n)
                acc[m][n] = __builtin_amdgcn_mfma_f32_16x16x32_bf16(af[m], bfr[n], acc[m][n], 0, 0, 0);
        __builtin_amdgcn_s_setprio(0);
        if (tk + 2 < nT) {
            if constexpr (NST == 6) WAIT_VM(6); else if constexpr (NST == 4) WAIT_VM(4); else WAIT_VM(3);
        } else if (tk + 1 < nT) {
            WAIT_VM(0);
        }
        if (tk + 1 < nT) __builtin_amdgcn_s_barrier();
        cur = (cur == 2) ? 0 : cur + 1;
    }
#undef STAGE
#undef WAIT_VM

    // epilogue: C/D layout col = lane&15, row = (lane>>4)*4 + j
    if (EPI == 0) {
#pragma unroll
        for (int m = 0; m < M_REP; ++m) {
            int grow = bm + wr * Mw + m * 16 + kgrp * 4;
#pragma unroll
            for (int n = 0; n < 4; ++n) {
                int gcol = bn + wc * 64 + n * 16 + l15;
                float bb = bias[gcol];
#pragma unroll
                for (int j = 0; j < 4; ++j)
                    __builtin_nontemporal_store(acc[m][n][j] + bb,
                                                &C[(size_t)(grow + j) * N + gcol]);
            }
        }
    } else {
        // wave's 64-col span = one head: softmax over head dim, scale by Vsum
        float bqv[4], ksv[4], vsv[4];
#pragma unroll
        for (int n = 0; n < 4; ++n) {
            int col = bn + wc * 64 + n * 16 + l15;
            bqv[n] = bias[col];
            ksv[n] = kvsum[col];
            vsv[n] = kvsum[HDK + col];
        }
#pragma unroll
        for (int m = 0; m < M_REP; ++m) {
            int grow = bm + wr * Mw + m * 16 + kgrp * 4;
#pragma unroll
            for (int j = 0; j < 4; ++j) {
                float x[4];
#pragma unroll
                for (int n = 0; n < 4; ++n)
                    x[n] = 0.125f * (acc[m][n][j] + bqv[n]) * ksv[n];
                float mx = fmaxf(fmaxf(x[0], x[1]), fmaxf(x[2], x[3]));
#pragma unroll
                for (int off = 8; off; off >>= 1) mx = fmaxf(mx, __shfl_xor(mx, off));
                float e[4], s = 0.f;
#pragma unroll
                for (int n = 0; n < 4; ++n) { e[n] = __expf(x[n] - mx); s += e[n]; }
#pragma unroll
                for (int off = 8; off; off >>= 1) s += __shfl_xor(s, off);
                float inv = 1.0f / s;
#pragma unroll
                for (int n = 0; n < 4; ++n) {
                    int col = bn + wc * 64 + n * 16 + l15;
                    R[(size_t)(grow + j) * N + col] = f2bf(e[n] * inv * vsv[n]);
                }
            }
        }
    }
}

// ---------- host launch ----------
extern "C" void kernel_launch(void* const* d_in, const int* in_sizes, int n_in,
                              void* d_out, int out_size, void* d_ws, size_t ws_size,
                              hipStream_t stream) {
    const float* target = (const float*)d_in[0];
    const float* source = (const float*)d_in[1];
    const float* value  = (const float*)d_in[2];
    const float* Wq = (const float*)d_in[3];
    const float* bq = (const float*)d_in[4];
    const float* Wk = (const float*)d_in[5];
    const float* bk = (const float*)d_in[6];
    const float* Wv = (const float*)d_in[7];
    const float* bv = (const float*)d_in[8];
    const float* Wo = (const float*)d_in[9];
    const float* bo = (const float*)d_in[10];
    float* out = (float*)d_out;

    char* ws = (char*)d_ws;
    float*          part1  = (float*)(ws);                      // 1.25MB
    float*          part2  = (float*)(ws + 0x180000);           // 512KB
    float*          kvsum  = (float*)(ws + 0x210000);           // 8KB
    unsigned short* tgt_bf = (unsigned short*)(ws + 0x400000);  // 8MB
    unsigned short* wq_t   = (unsigned short*)(ws + 0xC00000);  // 2MB
    unsigned short* wo_t   = (unsigned short*)(ws + 0xE00000);  // 8MB
    unsigned short* Rb     = (unsigned short*)(ws + 0x1600000); // 8MB

    // 1) fused prep: colsum partials + cast(target) + transpose(Wq) + transpose(Wo)
    mega1<<<7488, 256, 0, stream>>>(source, value, part1, target, tgt_bf, Wq, wq_t, Wo, wo_t);

    // 2) Ksum/Vsum GEMV + bias fold
    gemv_partial2<<<dim3(4, 64, 2), 256, 0, stream>>>(Wk, Wv, part1, part2);
    gemv_reduce<<<8, 256, 0, stream>>>(part2, bk, bv, kvsum);

    // 3) fused: S = target @ Wq; R = softmax_head(0.125*(S+bq)*Ksum) * Vsum (bf16)
    //    64x128 blocks, 2 waves, grid 512 (rect 8x8/XCD: gx=8 -> gDivR=1)
    gemm_ctd3<1, 64, 128, 1, 2><<<512, 128, 0, stream>>>(
        tgt_bf, wq_t, nullptr, bq, kvsum, Rb, HDK, DMODEL, /*gDivR=*/1);

    // 4) out = R @ Wo + bo
    //    256x128 blocks, 4 waves, grid 512 (gx=32 -> gDivR=4), NT C stores
    gemm_ctd3<0, 256, 128, 2, 2><<<512, 256, 0, stream>>>(
        Rb, wo_t, out, bo, nullptr, nullptr, DLLM, HDK, /*gDivR=*/4);
}

// Round 9
// 109.021 us; speedup vs baseline: 1.0065x; 1.0065x over previous
//
#include <hip/hip_runtime.h>

// ---------- constants (problem is fixed-shape) ----------
#define BB   16
#define PP   256
#define BP   4096        // B*P
#define DMODEL 1024
#define VV   1000
#define DLLM 4096
#define HH   16
#define DK   64
#define HDK  1024        // H*DK

using f32x4 = __attribute__((ext_vector_type(4))) float;
using s16x8 = __attribute__((ext_vector_type(8))) short;
using us8   = __attribute__((ext_vector_type(8))) unsigned short;

__device__ __forceinline__ unsigned short f2bf(float f) {
    unsigned int u = __builtin_bit_cast(unsigned int, f);
    u = (u + 0x7FFFu + ((u >> 16) & 1u)) >> 16;   // RNE
    return (unsigned short)u;
}

__device__ __forceinline__ void gload_lds16(const unsigned short* g, unsigned short* lds) {
    __builtin_amdgcn_global_load_lds(
        (const __attribute__((address_space(1))) void*)g,
        (__attribute__((address_space(3))) void*)lds,
        16, 0, 0);
}

// ---------- MEGA1: colsum_partial ∪ cast_bf16 ∪ transpose(Wq) ∪ transpose(Wo) ----------
// fully vectorized: float4 loads everywhere, ushort4/8 stores.
__device__ __forceinline__ void transpose_body(const float* __restrict__ src,
                                               unsigned short* __restrict__ dst,
                                               int R, int C, int bx, int by, int t,
                                               float (*tile)[33]) {
    int x = t & 7, y = t >> 3;                      // 8 x 32
    int c0 = bx * 32, r0 = by * 32;
    float4 v = *reinterpret_cast<const float4*>(&src[(size_t)(r0 + y) * C + c0 + x * 4]);
    tile[y][x * 4 + 0] = v.x; tile[y][x * 4 + 1] = v.y;
    tile[y][x * 4 + 2] = v.z; tile[y][x * 4 + 3] = v.w;
    __syncthreads();
    ushort4 o = make_ushort4(f2bf(tile[x * 4 + 0][y]), f2bf(tile[x * 4 + 1][y]),
                             f2bf(tile[x * 4 + 2][y]), f2bf(tile[x * 4 + 3][y]));
    *reinterpret_cast<ushort4*>(&dst[(size_t)(c0 + y) * R + r0 + x * 4]) = o;
}

__global__ void mega1(const float* __restrict__ src0, const float* __restrict__ src1,
                      float* __restrict__ part1,
                      const float* __restrict__ target, unsigned short* __restrict__ tgt_bf,
                      const float* __restrict__ Wq, unsigned short* __restrict__ wq_t,
                      const float* __restrict__ Wo, unsigned short* __restrict__ wo_t) {
    __shared__ float tile[32][33];
    int b = blockIdx.x, t = threadIdx.x;
    if (b < 320) {
        // colsum partials: z(2) x chunk(40) x xblk(4); float4 per lane
        int z = b / 160, rem = b % 160, y = rem >> 2, x = rem & 3;
        int col4 = x * 256 + t;                     // 0..1023 (of DLLM/4)
        const float4* src = reinterpret_cast<const float4*>(z ? src1 : src0);
        int r0 = y * 25;
        float4 acc = make_float4(0.f, 0.f, 0.f, 0.f);
        for (int r = 0; r < 25; ++r) {
            float4 v = src[(size_t)(r0 + r) * (DLLM / 4) + col4];
            acc.x += v.x; acc.y += v.y; acc.z += v.z; acc.w += v.w;
        }
        reinterpret_cast<float4*>(part1)[(size_t)(z * 40 + y) * (DLLM / 4) + col4] = acc;
    } else if (b < 320 + 2048) {
        // cast target f32 -> bf16, 8 elems/thread
        int idx = (b - 320) * 256 + t;              // < 524288
        float4 v0 = reinterpret_cast<const float4*>(target)[idx * 2];
        float4 v1 = reinterpret_cast<const float4*>(target)[idx * 2 + 1];
        us8 o = { f2bf(v0.x), f2bf(v0.y), f2bf(v0.z), f2bf(v0.w),
                  f2bf(v1.x), f2bf(v1.y), f2bf(v1.z), f2bf(v1.w) };
        *reinterpret_cast<us8*>(&tgt_bf[(size_t)idx * 8]) = o;
    } else if (b < 320 + 2048 + 1024) {
        int b2 = b - 2368;
        transpose_body(Wq, wq_t, DMODEL, HDK, b2 & 31, b2 >> 5, t, tile);
    } else {
        int b2 = b - 3392;
        transpose_body(Wo, wo_t, HDK, DLLM, b2 & 127, b2 >> 7, t, tile);
    }
}

// ---------- gemv_partial2 (inlines colsum_reduce) ----------
__global__ void gemv_partial2(const float* __restrict__ Wk, const float* __restrict__ Wv,
                              const float* __restrict__ part1, float* __restrict__ part2) {
    __shared__ float vec[64];
    int c     = blockIdx.x * 256 + threadIdx.x;
    int chunk = blockIdx.y;
    int z     = blockIdx.z;
    const float* W = z ? Wv : Wk;
    if (threadIdx.x < 64) {
        int r = chunk * 64 + threadIdx.x;
        float a = 0.f;
        for (int p = 0; p < 40; ++p)
            a += part1[(size_t)(z * 40 + p) * DLLM + r];
        vec[threadIdx.x] = a;
    }
    __syncthreads();
    float acc = 0.f;
    int r0 = chunk * 64;
    for (int r = 0; r < 64; ++r)
        acc += vec[r] * W[(size_t)(r0 + r) * HDK + c];
    part2[((z * 64 + chunk) * HDK) + c] = acc;
}

__global__ void gemv_reduce(const float* __restrict__ part,
                            const float* __restrict__ bk, const float* __restrict__ bv,
                            float* __restrict__ kvsum) {
    int idx = blockIdx.x * 256 + threadIdx.x;
    int z = idx >> 10, c = idx & 1023;
    float acc = 0.f;
    for (int ch = 0; ch < 64; ++ch) acc += part[(size_t)(z * 64 + ch) * HDK + c];
    acc += (float)VV * (z ? bv[c] : bk[c]);
    kvsum[idx] = acc;
}

// ---------- counted-vmcnt GEMM, 3-buffer BK=32, distance-2 prefetch ----------
// NEW this round: (1) rect-per-XCD swizzle — each XCD owns an 8x8 block rect
// so its L2 working set is A-panel + B-panel (<= ~6MB) instead of streaming
// the whole B matrix; (2) nontemporal C stores (EPI=0) keep the 64MB f32
// write burst from evicting A/B panels out of L2.
// Swizzle requires grid == 512 (64 blocks per XCD, rect 8x8).
// LDS swizzle: phys 16B-slot = logical ^ (super-row & 7), both sides (0 confl).
// EPI=0: C(f32)=A*B^T+bias (NT stores). EPI=1: fused per-head softmax -> bf16 R.
template<int EPI, int BMt, int BNt, int WM, int WN>
__global__ __launch_bounds__(WM * WN * 64, 2)
void gemm_ctd3(const unsigned short* __restrict__ A, const unsigned short* __restrict__ Bt,
               float* __restrict__ C, const float* __restrict__ bias,
               const float* __restrict__ kvsum, unsigned short* __restrict__ R,
               int N, int K, int gDivR) {
    constexpr int WAVES = WM * WN;
    constexpr int Mw = BMt / WM;
    constexpr int M_REP = Mw / 16;
    constexpr int NA = BMt * 32 / (WAVES * 512);   // A gloads per thread per stage
    constexpr int NB = BNt * 32 / (WAVES * 512);   // B gloads per thread per stage
    constexpr int NST = NA + NB;
    static_assert(BNt / WN == 64, "wave col span must be 64");
    static_assert(NA >= 1 && NB >= 1, "staging geometry");

    __shared__ __align__(16) unsigned short Asm[3][BMt * 32];
    __shared__ __align__(16) unsigned short Bsm[3][BNt * 32];

    // rect-per-XCD swizzle: xcd = bid&7 owns an 8(bm) x 8(bn) rect of blocks.
    // bm-group = xcd / gDivR, bn-group = xcd % gDivR  (gDivR = gx/8).
    const int xcd = blockIdx.x & 7, l = blockIdx.x >> 3;   // l in [0,64)
    const int bm = ((xcd / gDivR) * 8 + (l & 7)) * BMt;
    const int bn = ((xcd % gDivR) * 8 + (l >> 3)) * BNt;

    const int t = threadIdx.x;
    const int w = t >> 6, lane = t & 63;
    const int wr = w / WN, wc = w % WN;
    const int l15 = lane & 15, kgrp = lane >> 4;

    // staging map: issue covers 8 super-rows (128B each); lane -> sr+=lane>>3,
    // phys slot lane&7; global content for phys slot s at sr = (s ^ (sr&7)).
    size_t goffA[NA], goffB[NB];
    int ldsoA[NA], ldsoB[NB];
    {
        int s8 = lane & 7, jj = lane >> 3;
#pragma unroll
        for (int i = 0; i < NA; ++i) {
            int sr = (i * WAVES + w) * 8 + jj;
            int x = s8 ^ (sr & 7);
            goffA[i] = (size_t)(bm + sr * 2 + (x >> 2)) * K + (x & 3) * 8;
            ldsoA[i] = (i * WAVES + w) * 512;
        }
#pragma unroll
        for (int i = 0; i < NB; ++i) {
            int sr = (i * WAVES + w) * 8 + jj;
            int x = s8 ^ (sr & 7);
            goffB[i] = (size_t)(bn + sr * 2 + (x >> 2)) * K + (x & 3) * 8;
            ldsoB[i] = (i * WAVES + w) * 512;
        }
    }
    // swizzled ds_read offsets (ushort units)
    int ra[M_REP], rb[4];
#pragma unroll
    for (int m = 0; m < M_REP; ++m) {
        int r = wr * Mw + m * 16 + l15;
        int s8 = (kgrp + 4 * (r & 1)) ^ ((r >> 1) & 7);
        ra[m] = (r >> 1) * 64 + s8 * 8;
    }
#pragma unroll
    for (int n = 0; n < 4; ++n) {
        int r = wc * 64 + n * 16 + l15;
        int s8 = (kgrp + 4 * (r & 1)) ^ ((r >> 1) & 7);
        rb[n] = (r >> 1) * 64 + s8 * 8;
    }

    f32x4 acc[M_REP][4] = {};

#define STAGE(t_, b_) do { size_t k0_ = (size_t)(t_) * 32;             \
    _Pragma("unroll")                                                  \
    for (int i_ = 0; i_ < NA; ++i_)                                    \
        gload_lds16(A + goffA[i_] + k0_, &Asm[b_][ldsoA[i_]]);         \
    _Pragma("unroll")                                                  \
    for (int i_ = 0; i_ < NB; ++i_)                                    \
        gload_lds16(Bt + goffB[i_] + k0_, &Bsm[b_][ldsoB[i_]]); } while (0)

#define WAIT_VM(n_) asm volatile("s_waitcnt vmcnt(" #n_ ")" ::: "memory")

    const int nT = K >> 5;
    STAGE(0, 0); STAGE(1, 1);
    if constexpr (NST == 6) WAIT_VM(6); else if constexpr (NST == 4) WAIT_VM(4); else WAIT_VM(3);
    __builtin_amdgcn_s_barrier();

    int cur = 0;
    for (int tk = 0; tk < nT; ++tk) {
        s16x8 af[M_REP], bfr[4];
#pragma unroll
        for (int m = 0; m < M_REP; ++m)
            af[m] = *reinterpret_cast<const s16x8*>(&Asm[cur][ra[m]]);
#pragma unroll
        for (int n = 0; n < 4; ++n)
            bfr[n] = *reinterpret_cast<const s16x8*>(&Bsm[cur][rb[n]]);
        if (tk + 2 < nT) STAGE(tk + 2, cur == 0 ? 2 : cur - 1);   // (cur+2)%3
        __builtin_amdgcn_s_setprio(1);
#pragma unroll
        for (int m = 0; m < M_REP; ++m)
#pragma unroll
            for (int n = 0; n < 4; ++n)
                acc[m][n] = __builtin_amdgcn_mfma_f32_16x16x32_bf16(af[m], bfr[n], acc[m][n], 0, 0, 0);
        __builtin_amdgcn_s_setprio(0);
        if (tk + 2 < nT) {
            if constexpr (NST == 6) WAIT_VM(6); else if constexpr (NST == 4) WAIT_VM(4); else WAIT_VM(3);
        } else if (tk + 1 < nT) {
            WAIT_VM(0);
        }
        if (tk + 1 < nT) __builtin_amdgcn_s_barrier();
        cur = (cur == 2) ? 0 : cur + 1;
    }
#undef STAGE
#undef WAIT_VM

    // epilogue: C/D layout col = lane&15, row = (lane>>4)*4 + j
    if (EPI == 0) {
#pragma unroll
        for (int m = 0; m < M_REP; ++m) {
            int grow = bm + wr * Mw + m * 16 + kgrp * 4;
#pragma unroll
            for (int n = 0; n < 4; ++n) {
                int gcol = bn + wc * 64 + n * 16 + l15;
                float bb = bias[gcol];
#pragma unroll
                for (int j = 0; j < 4; ++j)
                    __builtin_nontemporal_store(acc[m][n][j] + bb,
                                                &C[(size_t)(grow + j) * N + gcol]);
            }
        }
    } else {
        // wave's 64-col span = one head: softmax over head dim, scale by Vsum
        float bqv[4], ksv[4], vsv[4];
#pragma unroll
        for (int n = 0; n < 4; ++n) {
            int col = bn + wc * 64 + n * 16 + l15;
            bqv[n] = bias[col];
            ksv[n] = kvsum[col];
            vsv[n] = kvsum[HDK + col];
        }
#pragma unroll
        for (int m = 0; m < M_REP; ++m) {
            int grow = bm + wr * Mw + m * 16 + kgrp * 4;
#pragma unroll
            for (int j = 0; j < 4; ++j) {
                float x[4];
#pragma unroll
                for (int n = 0; n < 4; ++n)
                    x[n] = 0.125f * (acc[m][n][j] + bqv[n]) * ksv[n];
                float mx = fmaxf(fmaxf(x[0], x[1]), fmaxf(x[2], x[3]));
#pragma unroll
                for (int off = 8; off; off >>= 1) mx = fmaxf(mx, __shfl_xor(mx, off));
                float e[4], s = 0.f;
#pragma unroll
                for (int n = 0; n < 4; ++n) { e[n] = __expf(x[n] - mx); s += e[n]; }
#pragma unroll
                for (int off = 8; off; off >>= 1) s += __shfl_xor(s, off);
                float inv = 1.0f / s;
#pragma unroll
                for (int n = 0; n < 4; ++n) {
                    int col = bn + wc * 64 + n * 16 + l15;
                    R[(size_t)(grow + j) * N + col] = f2bf(e[n] * inv * vsv[n]);
                }
            }
        }
    }
}

// ---------- host launch ----------
extern "C" void kernel_launch(void* const* d_in, const int* in_sizes, int n_in,
                              void* d_out, int out_size, void* d_ws, size_t ws_size,
                              hipStream_t stream) {
    const float* target = (const float*)d_in[0];
    const float* source = (const float*)d_in[1];
    const float* value  = (const float*)d_in[2];
    const float* Wq = (const float*)d_in[3];
    const float* bq = (const float*)d_in[4];
    const float* Wk = (const float*)d_in[5];
    const float* bk = (const float*)d_in[6];
    const float* Wv = (const float*)d_in[7];
    const float* bv = (const float*)d_in[8];
    const float* Wo = (const float*)d_in[9];
    const float* bo = (const float*)d_in[10];
    float* out = (float*)d_out;

    char* ws = (char*)d_ws;
    float*          part1  = (float*)(ws);                      // 1.25MB
    float*          part2  = (float*)(ws + 0x180000);           // 512KB
    float*          kvsum  = (float*)(ws + 0x210000);           // 8KB
    unsigned short* tgt_bf = (unsigned short*)(ws + 0x400000);  // 8MB
    unsigned short* wq_t   = (unsigned short*)(ws + 0xC00000);  // 2MB
    unsigned short* wo_t   = (unsigned short*)(ws + 0xE00000);  // 8MB
    unsigned short* Rb     = (unsigned short*)(ws + 0x1600000); // 8MB

    // 1) fused prep: colsum partials + cast(target) + transpose(Wq) + transpose(Wo)
    mega1<<<7488, 256, 0, stream>>>(source, value, part1, target, tgt_bf, Wq, wq_t, Wo, wo_t);

    // 2) Ksum/Vsum GEMV + bias fold
    gemv_partial2<<<dim3(4, 64, 2), 256, 0, stream>>>(Wk, Wv, part1, part2);
    gemv_reduce<<<8, 256, 0, stream>>>(part2, bk, bv, kvsum);

    // 3) fused: S = target @ Wq; R = softmax_head(0.125*(S+bq)*Ksum) * Vsum (bf16)
    //    64x128 blocks, 2 waves, grid 512 (rect 8x8/XCD: gx=8 -> gDivR=1)
    gemm_ctd3<1, 64, 128, 1, 2><<<512, 128, 0, stream>>>(
        tgt_bf, wq_t, nullptr, bq, kvsum, Rb, HDK, DMODEL, /*gDivR=*/1);

    // 4) out = R @ Wo + bo
    //    256x128 blocks, 4 waves, grid 512 (gx=32 -> gDivR=4), NT C stores
    gemm_ctd3<0, 256, 128, 2, 2><<<512, 256, 0, stream>>>(
        Rb, wo_t, out, bo, nullptr, nullptr, DLLM, HDK, /*gDivR=*/4);
}

// Round 10
// 93.147 us; speedup vs baseline: 1.1780x; 1.1704x over previous
//
#include <hip/hip_runtime.h>

// ---------- constants (problem is fixed-shape) ----------
#define BB   16
#define PP   256
#define BP   4096        // B*P
#define DMODEL 1024
#define VV   1000
#define DLLM 4096
#define HH   16
#define DK   64
#define HDK  1024        // H*DK

using f32x4 = __attribute__((ext_vector_type(4))) float;
using s16x8 = __attribute__((ext_vector_type(8))) short;
using us8   = __attribute__((ext_vector_type(8))) unsigned short;

__device__ __forceinline__ unsigned short f2bf(float f) {
    unsigned int u = __builtin_bit_cast(unsigned int, f);
    u = (u + 0x7FFFu + ((u >> 16) & 1u)) >> 16;   // RNE
    return (unsigned short)u;
}

__device__ __forceinline__ void gload_lds16(const unsigned short* g, unsigned short* lds) {
    __builtin_amdgcn_global_load_lds(
        (const __attribute__((address_space(1))) void*)g,
        (__attribute__((address_space(3))) void*)lds,
        16, 0, 0);
}

// ---------- MEGA1: colsum_partial ∪ cast_bf16 ∪ transpose(Wq) ∪ transpose(Wo) ----------
__device__ __forceinline__ void transpose_body(const float* __restrict__ src,
                                               unsigned short* __restrict__ dst,
                                               int R, int C, int bx, int by, int t,
                                               float (*tile)[33]) {
    int x = t & 7, y = t >> 3;                      // 8 x 32
    int c0 = bx * 32, r0 = by * 32;
    float4 v = *reinterpret_cast<const float4*>(&src[(size_t)(r0 + y) * C + c0 + x * 4]);
    tile[y][x * 4 + 0] = v.x; tile[y][x * 4 + 1] = v.y;
    tile[y][x * 4 + 2] = v.z; tile[y][x * 4 + 3] = v.w;
    __syncthreads();
    ushort4 o = make_ushort4(f2bf(tile[x * 4 + 0][y]), f2bf(tile[x * 4 + 1][y]),
                             f2bf(tile[x * 4 + 2][y]), f2bf(tile[x * 4 + 3][y]));
    *reinterpret_cast<ushort4*>(&dst[(size_t)(c0 + y) * R + r0 + x * 4]) = o;
}

__global__ void mega1(const float* __restrict__ src0, const float* __restrict__ src1,
                      float* __restrict__ part1,
                      const float* __restrict__ target, unsigned short* __restrict__ tgt_bf,
                      const float* __restrict__ Wq, unsigned short* __restrict__ wq_t,
                      const float* __restrict__ Wo, unsigned short* __restrict__ wo_t) {
    __shared__ float tile[32][33];
    int b = blockIdx.x, t = threadIdx.x;
    if (b < 320) {
        // colsum partials: z(2) x chunk(40) x xblk(4); float4 per lane
        int z = b / 160, rem = b % 160, y = rem >> 2, x = rem & 3;
        int col4 = x * 256 + t;
        const float4* src = reinterpret_cast<const float4*>(z ? src1 : src0);
        int r0 = y * 25;
        float4 acc = make_float4(0.f, 0.f, 0.f, 0.f);
        for (int r = 0; r < 25; ++r) {
            float4 v = src[(size_t)(r0 + r) * (DLLM / 4) + col4];
            acc.x += v.x; acc.y += v.y; acc.z += v.z; acc.w += v.w;
        }
        reinterpret_cast<float4*>(part1)[(size_t)(z * 40 + y) * (DLLM / 4) + col4] = acc;
    } else if (b < 320 + 2048) {
        // cast target f32 -> bf16, 8 elems/thread
        int idx = (b - 320) * 256 + t;
        float4 v0 = reinterpret_cast<const float4*>(target)[idx * 2];
        float4 v1 = reinterpret_cast<const float4*>(target)[idx * 2 + 1];
        us8 o = { f2bf(v0.x), f2bf(v0.y), f2bf(v0.z), f2bf(v0.w),
                  f2bf(v1.x), f2bf(v1.y), f2bf(v1.z), f2bf(v1.w) };
        *reinterpret_cast<us8*>(&tgt_bf[(size_t)idx * 8]) = o;
    } else if (b < 320 + 2048 + 1024) {
        int b2 = b - 2368;
        transpose_body(Wq, wq_t, DMODEL, HDK, b2 & 31, b2 >> 5, t, tile);
    } else {
        int b2 = b - 3392;
        transpose_body(Wo, wo_t, HDK, DLLM, b2 & 127, b2 >> 7, t, tile);
    }
}

// ---------- gemv_partial2 (inlines colsum_reduce) ----------
__global__ void gemv_partial2(const float* __restrict__ Wk, const float* __restrict__ Wv,
                              const float* __restrict__ part1, float* __restrict__ part2) {
    __shared__ float vec[64];
    int c     = blockIdx.x * 256 + threadIdx.x;
    int chunk = blockIdx.y;
    int z     = blockIdx.z;
    const float* W = z ? Wv : Wk;
    if (threadIdx.x < 64) {
        int r = chunk * 64 + threadIdx.x;
        float a = 0.f;
        for (int p = 0; p < 40; ++p)
            a += part1[(size_t)(z * 40 + p) * DLLM + r];
        vec[threadIdx.x] = a;
    }
    __syncthreads();
    float acc = 0.f;
    int r0 = chunk * 64;
    for (int r = 0; r < 64; ++r)
        acc += vec[r] * W[(size_t)(r0 + r) * HDK + c];
    part2[((z * 64 + chunk) * HDK) + c] = acc;
}

__global__ void gemv_reduce(const float* __restrict__ part,
                            const float* __restrict__ bk, const float* __restrict__ bv,
                            float* __restrict__ kvsum) {
    int idx = blockIdx.x * 256 + threadIdx.x;
    int z = idx >> 10, c = idx & 1023;
    float acc = 0.f;
    for (int ch = 0; ch < 64; ++ch) acc += part[(size_t)(z * 64 + ch) * HDK + c];
    acc += (float)VV * (z ? bv[c] : bk[c]);
    kvsum[idx] = acc;
}

// ---------- counted-vmcnt GEMM, 3-buffer BK=32, distance-2 prefetch ----------
// Rect-per-XCD swizzle (kept from r7 — FETCH 37->24.6MB): xcd = bid&7 owns a
// BMPX x BNPX rect of blocks; bm-group = xcd/NXBN, bn-group = xcd%NXBN. Sized
// so each XCD's A-stripe + B-panels approach its 4MB L2.
// NT stores REVERTED (r7: scalar-dword NT -> 64B partial-line HBM writes,
// WRITE 65.5->84MB, +35% time). Plain cached stores.
// LDS swizzle: phys 16B-slot = logical ^ (super-row & 7), both sides (0 confl).
// EPI=0: C(f32)=A*B^T+bias. EPI=1: fused per-head softmax -> bf16 R.
template<int EPI, int BMt, int BNt, int WM, int WN, int BMPX, int NXBN, int BNPX>
__global__ __launch_bounds__(WM * WN * 64, 2)
void gemm_ctd3(const unsigned short* __restrict__ A, const unsigned short* __restrict__ Bt,
               float* __restrict__ C, const float* __restrict__ bias,
               const float* __restrict__ kvsum, unsigned short* __restrict__ R,
               int N, int K) {
    constexpr int WAVES = WM * WN;
    constexpr int Mw = BMt / WM;
    constexpr int M_REP = Mw / 16;
    constexpr int NA = BMt * 32 / (WAVES * 512);   // A gloads per thread per stage
    constexpr int NB = BNt * 32 / (WAVES * 512);   // B gloads per thread per stage
    constexpr int NST = NA + NB;
    static_assert(BNt / WN == 64, "wave col span must be 64");
    static_assert(NA >= 1 && NB >= 1, "staging geometry");

    __shared__ __align__(16) unsigned short Asm[3][BMt * 32];
    __shared__ __align__(16) unsigned short Bsm[3][BNt * 32];

    // rect-per-XCD swizzle
    const int xcd = blockIdx.x & 7, l = blockIdx.x >> 3;   // l in [0, BMPX*BNPX)
    const int bm = ((xcd / NXBN) * BMPX + (l % BMPX)) * BMt;
    const int bn = ((xcd % NXBN) * BNPX + (l / BMPX)) * BNt;

    const int t = threadIdx.x;
    const int w = t >> 6, lane = t & 63;
    const int wr = w / WN, wc = w % WN;
    const int l15 = lane & 15, kgrp = lane >> 4;

    // staging map: issue covers 8 super-rows (128B each); lane -> sr+=lane>>3,
    // phys slot lane&7; global content for phys slot s at sr = (s ^ (sr&7)).
    size_t goffA[NA], goffB[NB];
    int ldsoA[NA], ldsoB[NB];
    {
        int s8 = lane & 7, jj = lane >> 3;
#pragma unroll
        for (int i = 0; i < NA; ++i) {
            int sr = (i * WAVES + w) * 8 + jj;
            int x = s8 ^ (sr & 7);
            goffA[i] = (size_t)(bm + sr * 2 + (x >> 2)) * K + (x & 3) * 8;
            ldsoA[i] = (i * WAVES + w) * 512;
        }
#pragma unroll
        for (int i = 0; i < NB; ++i) {
            int sr = (i * WAVES + w) * 8 + jj;
            int x = s8 ^ (sr & 7);
            goffB[i] = (size_t)(bn + sr * 2 + (x >> 2)) * K + (x & 3) * 8;
            ldsoB[i] = (i * WAVES + w) * 512;
        }
    }
    // swizzled ds_read offsets (ushort units)
    int ra[M_REP], rb[4];
#pragma unroll
    for (int m = 0; m < M_REP; ++m) {
        int r = wr * Mw + m * 16 + l15;
        int s8 = (kgrp + 4 * (r & 1)) ^ ((r >> 1) & 7);
        ra[m] = (r >> 1) * 64 + s8 * 8;
    }
#pragma unroll
    for (int n = 0; n < 4; ++n) {
        int r = wc * 64 + n * 16 + l15;
        int s8 = (kgrp + 4 * (r & 1)) ^ ((r >> 1) & 7);
        rb[n] = (r >> 1) * 64 + s8 * 8;
    }

    f32x4 acc[M_REP][4] = {};

#define STAGE(t_, b_) do { size_t k0_ = (size_t)(t_) * 32;             \
    _Pragma("unroll")                                                  \
    for (int i_ = 0; i_ < NA; ++i_)                                    \
        gload_lds16(A + goffA[i_] + k0_, &Asm[b_][ldsoA[i_]]);         \
    _Pragma("unroll")                                                  \
    for (int i_ = 0; i_ < NB; ++i_)                                    \
        gload_lds16(Bt + goffB[i_] + k0_, &Bsm[b_][ldsoB[i_]]); } while (0)

#define WAIT_NST() do {                                                 \
    if constexpr (NST == 6) asm volatile("s_waitcnt vmcnt(6)" ::: "memory"); \
    else if constexpr (NST == 4) asm volatile("s_waitcnt vmcnt(4)" ::: "memory"); \
    else if constexpr (NST == 3) asm volatile("s_waitcnt vmcnt(3)" ::: "memory"); \
    else asm volatile("s_waitcnt vmcnt(2)" ::: "memory"); } while (0)

    const int nT = K >> 5;
    STAGE(0, 0); STAGE(1, 1);
    WAIT_NST();
    __builtin_amdgcn_s_barrier();

    int cur = 0;
    for (int tk = 0; tk < nT; ++tk) {
        s16x8 af[M_REP], bfr[4];
#pragma unroll
        for (int m = 0; m < M_REP; ++m)
            af[m] = *reinterpret_cast<const s16x8*>(&Asm[cur][ra[m]]);
#pragma unroll
        for (int n = 0; n < 4; ++n)
            bfr[n] = *reinterpret_cast<const s16x8*>(&Bsm[cur][rb[n]]);
        if (tk + 2 < nT) STAGE(tk + 2, cur == 0 ? 2 : cur - 1);   // (cur+2)%3
        __builtin_amdgcn_s_setprio(1);
#pragma unroll
        for (int m = 0; m < M_REP; ++m)
#pragma unroll
            for (int n = 0; n < 4; ++n)
                acc[m][n] = __builtin_amdgcn_mfma_f32_16x16x32_bf16(af[m], bfr[n], acc[m][n], 0, 0, 0);
        __builtin_amdgcn_s_setprio(0);
        if (tk + 2 < nT) {
            WAIT_NST();
        } else if (tk + 1 < nT) {
            asm volatile("s_waitcnt vmcnt(0)" ::: "memory");
        }
        if (tk + 1 < nT) __builtin_amdgcn_s_barrier();
        cur = (cur == 2) ? 0 : cur + 1;
    }
#undef STAGE
#undef WAIT_NST

    // epilogue: C/D layout col = lane&15, row = (lane>>4)*4 + j
    if (EPI == 0) {
#pragma unroll
        for (int m = 0; m < M_REP; ++m) {
            int grow = bm + wr * Mw + m * 16 + kgrp * 4;
#pragma unroll
            for (int n = 0; n < 4; ++n) {
                int gcol = bn + wc * 64 + n * 16 + l15;
                float bb = bias[gcol];
#pragma unroll
                for (int j = 0; j < 4; ++j)
                    C[(size_t)(grow + j) * N + gcol] = acc[m][n][j] + bb;
            }
        }
    } else {
        // wave's 64-col span = one head: softmax over head dim, scale by Vsum
        float bqv[4], ksv[4], vsv[4];
#pragma unroll
        for (int n = 0; n < 4; ++n) {
            int col = bn + wc * 64 + n * 16 + l15;
            bqv[n] = bias[col];
            ksv[n] = kvsum[col];
            vsv[n] = kvsum[HDK + col];
        }
#pragma unroll
        for (int m = 0; m < M_REP; ++m) {
            int grow = bm + wr * Mw + m * 16 + kgrp * 4;
#pragma unroll
            for (int j = 0; j < 4; ++j) {
                float x[4];
#pragma unroll
                for (int n = 0; n < 4; ++n)
                    x[n] = 0.125f * (acc[m][n][j] + bqv[n]) * ksv[n];
                float mx = fmaxf(fmaxf(x[0], x[1]), fmaxf(x[2], x[3]));
#pragma unroll
                for (int off = 8; off; off >>= 1) mx = fmaxf(mx, __shfl_xor(mx, off));
                float e[4], s = 0.f;
#pragma unroll
                for (int n = 0; n < 4; ++n) { e[n] = __expf(x[n] - mx); s += e[n]; }
#pragma unroll
                for (int off = 8; off; off >>= 1) s += __shfl_xor(s, off);
                float inv = 1.0f / s;
#pragma unroll
                for (int n = 0; n < 4; ++n) {
                    int col = bn + wc * 64 + n * 16 + l15;
                    R[(size_t)(grow + j) * N + col] = f2bf(e[n] * inv * vsv[n]);
                }
            }
        }
    }
}

// ---------- host launch ----------
extern "C" void kernel_launch(void* const* d_in, const int* in_sizes, int n_in,
                              void* d_out, int out_size, void* d_ws, size_t ws_size,
                              hipStream_t stream) {
    const float* target = (const float*)d_in[0];
    const float* source = (const float*)d_in[1];
    const float* value  = (const float*)d_in[2];
    const float* Wq = (const float*)d_in[3];
    const float* bq = (const float*)d_in[4];
    const float* Wk = (const float*)d_in[5];
    const float* bk = (const float*)d_in[6];
    const float* Wv = (const float*)d_in[7];
    const float* bv = (const float*)d_in[8];
    const float* Wo = (const float*)d_in[9];
    const float* bo = (const float*)d_in[10];
    float* out = (float*)d_out;

    char* ws = (char*)d_ws;
    float*          part1  = (float*)(ws);                      // 1.25MB
    float*          part2  = (float*)(ws + 0x180000);           // 512KB
    float*          kvsum  = (float*)(ws + 0x210000);           // 8KB
    unsigned short* tgt_bf = (unsigned short*)(ws + 0x400000);  // 8MB
    unsigned short* wq_t   = (unsigned short*)(ws + 0xC00000);  // 2MB
    unsigned short* wo_t   = (unsigned short*)(ws + 0xE00000);  // 8MB
    unsigned short* Rb     = (unsigned short*)(ws + 0x1600000); // 8MB

    // 1) fused prep: colsum partials + cast(target) + transpose(Wq) + transpose(Wo)
    mega1<<<7488, 256, 0, stream>>>(source, value, part1, target, tgt_bf, Wq, wq_t, Wo, wo_t);

    // 2) Ksum/Vsum GEMV + bias fold
    gemv_partial2<<<dim3(4, 64, 2), 256, 0, stream>>>(Wk, Wv, part1, part2);
    gemv_reduce<<<8, 256, 0, stream>>>(part2, bk, bv, kvsum);

    // 3) fused: S = target @ Wq; R = softmax_head(0.125*(S+bq)*Ksum) * Vsum (bf16)
    //    64x128 blocks (gx=8 -> A traffic 16MB, was 128MB at BN=64), grid 512,
    //    2 blocks/CU, rect 16bm x 4bn per XCD (A 2MB + B 1MB in L2).
    gemm_ctd3<1, 64, 128, 2, 2, 16, 2, 4><<<512, 256, 0, stream>>>(
        tgt_bf, wq_t, nullptr, bq, kvsum, Rb, HDK, DMODEL);

    // 4) out = R @ Wo + bo
    //    256x128 blocks, grid 512, 2 blocks/CU, rect 8bm x 8bn per XCD,
    //    plain cached C stores (NT reverted).
    gemm_ctd3<0, 256, 128, 2, 2, 8, 4, 8><<<512, 256, 0, stream>>>(
        Rb, wo_t, out, bo, nullptr, nullptr, DLLM, HDK);
}